// Round 13
// baseline (494.990 us; speedup 1.0000x reference)
//
#include <hip/hip_runtime.h>
#include <cstddef>
#include <cstdint>

// Problem constants
static constexpr int M_ROWS  = 32768;   // B*T
static constexpr int D_INK   = 1024;
static constexpr int D_HID   = 512;
static constexpr int D_CODE_ = 256;
static constexpr int N_CODES_= 128;

// fp16 single-product pairwise-d2 gap jitter sigma ~= 0.023 -> TAU = 6.5 sigma
static constexpr float TAU_GAP = 0.15f;

using f16x8 = __attribute__((ext_vector_type(8))) _Float16;
using f32x4 = __attribute__((ext_vector_type(4))) float;

__device__ __forceinline__ float rdlane(float v, int kk) {
    return __uint_as_float(__builtin_amdgcn_readlane(__float_as_uint(v), kk));
}

// ---------------------------------------------------------------------------
// Packed panel format: one panel = one (128-row tile) x (32-k step):
//   panel[(kq*128 + rc)*8 + j] = src[tile*128 + rc][ks*32 + kq*8 + j]
// 4096 x fp16 = 8 KB contiguous; frag-linear == the LDS layout the MFMA
// fragment reads want, so global->LDS DMA is fully coalesced AND linear.
// ---------------------------------------------------------------------------

__device__ __forceinline__ void dma16(const void* g, void* l) {
    __builtin_amdgcn_global_load_lds(
        (const __attribute__((address_space(1))) void*)g,
        (__attribute__((address_space(3))) void*)l, 16, 0, 0);
}

// stage one 8 KB panel into LDS: 8 dma16 instrs, 2 per wave, lane-contiguous
__device__ __forceinline__ void stage_panel(const _Float16* __restrict__ p,
                                            _Float16* dst, int w, int lane)
{
    #pragma unroll
    for (int ii = 0; ii < 2; ++ii) {
        const int I = 2 * w + ii;           // 0..7 (wave-uniform)
        dma16(p + (size_t)I * 512 + lane * 8, dst + (size_t)I * 512);
    }
}

// one BK=32 compute step: 4x4 fragment tile per wave, single fp16 product
__device__ __forceinline__ void mfma_tile(const _Float16* sA, const _Float16* sB,
                                          int wm, int wn, int kq, int lm,
                                          f32x4 (&acc)[4][4])
{
    f16x8 a[4];
    #pragma unroll
    for (int fm = 0; fm < 4; ++fm)
        a[fm] = *(const f16x8*)(sA + (kq * 128 + wm * 64 + fm * 16 + lm) * 8);
    #pragma unroll
    for (int fn = 0; fn < 4; ++fn) {
        const f16x8 b = *(const f16x8*)(sB + (kq * 128 + wn * 64 + fn * 16 + lm) * 8);
        #pragma unroll
        for (int fm = 0; fm < 4; ++fm)
            acc[fm][fn] = __builtin_amdgcn_mfma_f32_16x16x32_f16(a[fm], b, acc[fm][fn], 0, 0, 0);
    }
}

// bijective XCD swizzle (nwg % 8 == 0): consecutive logical ids -> same XCD L2
__device__ __forceinline__ int xcd_swz(int bid, int nwg) {
    const int q = nwg >> 3;
    return (bid & 7) * q + (bid >> 3);
}

// ---------------------------------------------------------------------------
// prep: codebook -> packed fp16 panels (B-side) + fp32 transposed copy
// (for coalesced fixup distance reads), exact per-code norms, zero accums.
// ---------------------------------------------------------------------------
__global__ __launch_bounds__(256)
void prep_cb_kernel(const float* __restrict__ cb, _Float16* __restrict__ cbP,
                    float* __restrict__ cbT,
                    float* __restrict__ cbnorm, float* __restrict__ accum,
                    int* __restrict__ cnt)
{
    const int j = blockIdx.x;      // code 0..127
    const int t = threadIdx.x;     // dim 0..255
    const float v = cb[j * D_CODE_ + t];
    const int ks = t >> 5, kq = (t >> 3) & 3, jj = t & 7;
    cbP[((size_t)ks * 512 + kq * 128 + j) * 8 + jj] = (_Float16)v;
    cbT[(size_t)t * N_CODES_ + j] = v;

    __shared__ float sr[256];
    sr[t] = v * v;
    __syncthreads();
    for (int s = 128; s >= 1; s >>= 1) {
        if (t < s) sr[t] += sr[t + s];
        __syncthreads();
    }
    if (t == 0) cbnorm[j] = sr[0];
    if (j == 0 && t < 2) accum[t] = 0.0f;
    if (j == 0 && t == 2) *cnt = 0;
}

// ---------------------------------------------------------------------------
// pack_w: W [K][N] fp32 -> B-side panels (n-tiles of 128, k-steps of 32).
// ---------------------------------------------------------------------------
__global__ __launch_bounds__(256)
void pack_w_kernel(const float* __restrict__ W, _Float16* __restrict__ WP,
                   int Kd, int Nd)
{
    const int ks = blockIdx.x, nt = blockIdx.y;
    const int t = threadIdx.x;
    _Float16* dst = WP + ((size_t)nt * (Kd >> 5) + ks) * 4096;
    #pragma unroll
    for (int half = 0; half < 2; ++half) {
        const int f = half * 256 + t;
        const int nc = f & 127, kq = f >> 7;
        f16x8 v;
        #pragma unroll
        for (int j = 0; j < 8; ++j)
            v[j] = (_Float16)W[(size_t)(ks * 32 + kq * 8 + j) * Nd + nt * 128 + nc];
        *(f16x8*)(dst + (size_t)f * 8) = v;
    }
}

// ---------------------------------------------------------------------------
// pack_x: x fp32 [M][1024] -> A-side fp16 panels.  Coalesced reads,
// LDS-tiled, contiguous panel writes.  grid = (M/128, 8).
// ---------------------------------------------------------------------------
__global__ __launch_bounds__(256)
void pack_x_kernel(const float* __restrict__ X, _Float16* __restrict__ XP)
{
    __shared__ _Float16 sh[128][136];   // 272 B rows: 16B-aligned frag reads
    const int t  = threadIdx.x;
    const int mt = blockIdx.x;          // m-tile
    const int kc = blockIdx.y;          // 128-wide k chunk (4 k-steps)

    const float* src = X + (size_t)mt * 128 * D_INK + kc * 128;
    #pragma unroll
    for (int i = 0; i < 16; ++i) {
        const int idx = i * 256 + t;           // 0..4095
        const int row = idx >> 5, c4 = idx & 31;
        const float4 v = *(const float4*)(src + (size_t)row * D_INK + c4 * 4);
        _Float16* d = &sh[row][c4 * 4];
        d[0] = (_Float16)v.x; d[1] = (_Float16)v.y;
        d[2] = (_Float16)v.z; d[3] = (_Float16)v.w;
    }
    __syncthreads();

    _Float16* dst = XP + ((size_t)mt * 32 + kc * 4) * 4096;
    #pragma unroll
    for (int s = 0; s < 4; ++s) {
        #pragma unroll
        for (int half = 0; half < 2; ++half) {
            const int f = half * 256 + t;
            const int rc = f & 127, kq = f >> 7;
            const f16x8 v = *(const f16x8*)(&sh[rc][s * 32 + kq * 8]);
            *(f16x8*)(dst + (size_t)s * 4096 + (size_t)f * 8) = v;
        }
    }
}

// ---------------------------------------------------------------------------
// GEMM1: h = relu(x @ W1 + b1).  All-packed-DMA staging, dbuf LDS (32 KB),
// one __syncthreads per K-step, 4 blocks/CU, XCD-swizzled n-fast grid.
// Output written directly in gemm2's packed-A layout.
// ---------------------------------------------------------------------------
__global__ __launch_bounds__(256, 4)
void gemm1_kernel(const _Float16* __restrict__ AP, const _Float16* __restrict__ BP,
                  const float* __restrict__ bias, _Float16* __restrict__ CP)
{
    __shared__ _Float16 lds[2][2][4096];   // [buf][A,B]  32 KB

    const int tid  = threadIdx.x;
    const int lane = tid & 63;
    const int w    = tid >> 6;
    const int wm = w >> 1, wn = w & 1;
    const int kq = lane >> 4, lm = lane & 15;

    const int swz = xcd_swz(blockIdx.x, (M_ROWS / 128) * (D_HID / 128));
    const int n0 = (swz & 3) * 128;
    const int m0 = (swz >> 2) * 128;

    const _Float16* Apan = AP + ((size_t)(m0 >> 7) * 32) * 4096;
    const _Float16* Bpan = BP + ((size_t)(n0 >> 7) * 32) * 4096;

    f32x4 acc[4][4] = {};

    stage_panel(Apan, &lds[0][0][0], w, lane);
    stage_panel(Bpan, &lds[0][1][0], w, lane);

    constexpr int NSTEP = D_INK / 32;
    for (int t = 0; t < NSTEP; ++t) {
        const int cur = t & 1, nxt = cur ^ 1;
        __syncthreads();               // buf[cur] staged & visible, buf[nxt] free
        if (t + 1 < NSTEP) {
            stage_panel(Apan + (size_t)(t + 1) * 4096, &lds[nxt][0][0], w, lane);
            stage_panel(Bpan + (size_t)(t + 1) * 4096, &lds[nxt][1][0], w, lane);
        }
        mfma_tile(&lds[cur][0][0], &lds[cur][1][0], wm, wn, kq, lm, acc);
    }

    // epilogue: relu; write in gemm2-packed-A layout (NT=16 over D_HID)
    #pragma unroll
    for (int fn = 0; fn < 4; ++fn) {
        const int col = n0 + wn * 64 + fn * 16 + lm;
        const float bv = bias[col];
        #pragma unroll
        for (int fm = 0; fm < 4; ++fm) {
            #pragma unroll
            for (int r = 0; r < 4; ++r) {
                const int row = m0 + wm * 64 + fm * 16 + kq * 4 + r;
                const float v = fmaxf(acc[fm][fn][r] + bv, 0.0f);
                CP[(((size_t)(row >> 7) * 16 + (col >> 5)) * 512
                    + (size_t)((col >> 3) & 3) * 128 + (row & 127)) * 8 + (col & 7)]
                    = (_Float16)v;
            }
        }
    }
}

// ---------------------------------------------------------------------------
// GEMM2: enc = h @ W2 + b2 (+ sum(enc^2) atomic).  Packed in, packed out.
// ---------------------------------------------------------------------------
__global__ __launch_bounds__(256, 4)
void gemm2_kernel(const _Float16* __restrict__ AP, const _Float16* __restrict__ BP,
                  const float* __restrict__ bias, _Float16* __restrict__ CP,
                  float* __restrict__ accum)
{
    __shared__ _Float16 lds[2][2][4096];

    const int tid  = threadIdx.x;
    const int lane = tid & 63;
    const int w    = tid >> 6;
    const int wm = w >> 1, wn = w & 1;
    const int kq = lane >> 4, lm = lane & 15;

    const int swz = xcd_swz(blockIdx.x, (M_ROWS / 128) * (D_CODE_ / 128));
    const int n0 = (swz & 1) * 128;
    const int m0 = (swz >> 1) * 128;

    const _Float16* Apan = AP + ((size_t)(m0 >> 7) * 16) * 4096;
    const _Float16* Bpan = BP + ((size_t)(n0 >> 7) * 16) * 4096;

    f32x4 acc[4][4] = {};

    stage_panel(Apan, &lds[0][0][0], w, lane);
    stage_panel(Bpan, &lds[0][1][0], w, lane);

    constexpr int NSTEP = D_HID / 32;
    for (int t = 0; t < NSTEP; ++t) {
        const int cur = t & 1, nxt = cur ^ 1;
        __syncthreads();
        if (t + 1 < NSTEP) {
            stage_panel(Apan + (size_t)(t + 1) * 4096, &lds[nxt][0][0], w, lane);
            stage_panel(Bpan + (size_t)(t + 1) * 4096, &lds[nxt][1][0], w, lane);
        }
        mfma_tile(&lds[cur][0][0], &lds[cur][1][0], wm, wn, kq, lm, acc);
    }

    float sumsq = 0.0f;
    #pragma unroll
    for (int fn = 0; fn < 4; ++fn) {
        const int col = n0 + wn * 64 + fn * 16 + lm;
        const float bv = bias[col];
        #pragma unroll
        for (int fm = 0; fm < 4; ++fm) {
            #pragma unroll
            for (int r = 0; r < 4; ++r) {
                const int row = m0 + wm * 64 + fm * 16 + kq * 4 + r;
                const float v = acc[fm][fn][r] + bv;
                sumsq = fmaf(v, v, sumsq);
                CP[(((size_t)(row >> 7) * 8 + (col >> 5)) * 512
                    + (size_t)((col >> 3) & 3) * 128 + (row & 127)) * 8 + (col & 7)]
                    = (_Float16)v;
            }
        }
    }
    #pragma unroll
    for (int mk = 1; mk <= 32; mk <<= 1) sumsq += __shfl_xor(sumsq, mk);
    if (lane == 0) atomicAdd(&accum[1], sumsq);
}

// ---------------------------------------------------------------------------
// dist: dots = enc @ cb^T (one n-block = all 128 codes); argmin epilogue
// with second-best gap flagging + min-term loss sum.
// ---------------------------------------------------------------------------
__global__ __launch_bounds__(256, 4)
void dist_kernel(const _Float16* __restrict__ AP, const _Float16* __restrict__ BP,
                 const float* __restrict__ cbn,
                 float* __restrict__ outIdx, float* __restrict__ accum,
                 int* __restrict__ cnt, int* __restrict__ list)
{
    __shared__ _Float16 lds[2][2][4096];

    const int tid  = threadIdx.x;
    const int lane = tid & 63;
    const int w    = tid >> 6;
    const int wm = w >> 1, wn = w & 1;
    const int kq = lane >> 4, lm = lane & 15;
    const int m0 = blockIdx.x * 128;

    float cbn_l[4];
    #pragma unroll
    for (int fn = 0; fn < 4; ++fn) cbn_l[fn] = cbn[wn * 64 + fn * 16 + lm];

    const _Float16* Apan = AP + ((size_t)(m0 >> 7) * 8) * 4096;

    f32x4 acc[4][4] = {};

    stage_panel(Apan, &lds[0][0][0], w, lane);
    stage_panel(BP,   &lds[0][1][0], w, lane);

    constexpr int NSTEP = D_CODE_ / 32;
    for (int t = 0; t < NSTEP; ++t) {
        const int cur = t & 1, nxt = cur ^ 1;
        __syncthreads();
        if (t + 1 < NSTEP) {
            stage_panel(Apan + (size_t)(t + 1) * 4096, &lds[nxt][0][0], w, lane);
            stage_panel(BP   + (size_t)(t + 1) * 4096, &lds[nxt][1][0], w, lane);
        }
        mfma_tile(&lds[cur][0][0], &lds[cur][1][0], wm, wn, kq, lm, acc);
    }

    __syncthreads();   // all LDS reads done before reuse as epilogue scratch
    float* eb1 = (float*)&lds[0][0][0];        // [2][128]
    float* eb2 = eb1 + 256;
    int*   eix = (int*)(eb2 + 256);

    #pragma unroll
    for (int fm = 0; fm < 4; ++fm) {
        #pragma unroll
        for (int r = 0; r < 4; ++r) {
            float b1v = 3.4e38f, b2v = 3.4e38f; int bi = 0;
            #pragma unroll
            for (int fn = 0; fn < 4; ++fn) {
                const float v = fmaf(-2.0f, acc[fm][fn][r], cbn_l[fn]);
                if (v < b1v) { b2v = b1v; b1v = v; bi = wn * 64 + fn * 16 + lm; }
                else if (v < b2v) b2v = v;
            }
            #pragma unroll
            for (int mk = 1; mk <= 8; mk <<= 1) {
                const float o1 = __shfl_xor(b1v, mk);
                const float o2 = __shfl_xor(b2v, mk);
                const int   oi = __shfl_xor(bi,  mk);
                if (o1 < b1v || (o1 == b1v && oi < bi)) { b2v = fminf(b1v, o2); b1v = o1; bi = oi; }
                else b2v = fminf(b2v, o1);
            }
            const int rl = wm * 64 + fm * 16 + kq * 4 + r;
            if (lm == 0) { eb1[wn * 128 + rl] = b1v; eb2[wn * 128 + rl] = b2v; eix[wn * 128 + rl] = bi; }
        }
    }
    __syncthreads();

    if (tid < 128) {
        const int rl = tid;
        const float a1 = eb1[rl], a2 = eb2[rl]; const int ai = eix[rl];
        const float o1 = eb1[128 + rl], o2 = eb2[128 + rl]; const int oi = eix[128 + rl];
        float B1, B2; int BI;
        if (o1 < a1 || (o1 == a1 && oi < ai)) { B1 = o1; BI = oi; B2 = fminf(a1, o2); }
        else                                  { B1 = a1; BI = ai; B2 = fminf(a2, o1); }
        outIdx[m0 + rl] = (float)BI;
        if (B2 - B1 < TAU_GAP) { const int p = atomicAdd(cnt, 1); list[p] = m0 + rl; }
        float s = B1;
        #pragma unroll
        for (int mk = 1; mk <= 32; mk <<= 1) s += __shfl_xor(s, mk);
        if (lane == 0) atomicAdd(&accum[0], s);
    }
}

// ---------------------------------------------------------------------------
// fixup v5: exact fp32 recompute, ONE WAVE PER ROW, ZERO barriers.
// Each wave owns a flagged row end-to-end using wave-private LDS rows;
// idle waves skip.  W1/W2/cbT reads lane-coalesced (float4/float2);
// broadcasts via v_readlane of per-64-chunk LDS-loaded registers.
// Accumulation order: single k-ascending fma chain per output element
// (identical to all previous passing versions).
// ---------------------------------------------------------------------------
__global__ __launch_bounds__(512)
void fixup_kernel(const float* __restrict__ x, const float* __restrict__ W1,
                  const float* __restrict__ b1, const float* __restrict__ W2,
                  const float* __restrict__ b2, const float* __restrict__ cbT,
                  const float* __restrict__ cbnorm,
                  const int* __restrict__ cnt, const int* __restrict__ list,
                  float* __restrict__ outIdx)
{
    __shared__ float xr[8][1024];   // 32 KB (wave-private rows)
    __shared__ float hr[8][512];    // 16 KB
    __shared__ float er[8][256];    //  8 KB   -> 56 KB total, 2 blocks/CU

    const int tid  = threadIdx.x;   // 0..511
    const int lane = tid & 63;
    const int wid  = tid >> 6;      // wave 0..7 == row slot
    const int n = *cnt;
    const int ngroups = (n + 7) >> 3;

    for (int g = blockIdx.x; g < ngroups; g += gridDim.x) {
        const int ridx = g * 8 + wid;
        if (ridx >= n) continue;              // no barriers -> safe to skip
        const int row = list[ridx];
        const float* xrow = x + (size_t)row * D_INK;

        // stage x row into wave-private LDS (coalesced float4)
        #pragma unroll
        for (int i = 0; i < 4; ++i)
            *(float4*)&xr[wid][i * 256 + lane * 4] =
                *(const float4*)(xrow + i * 256 + lane * 4);

        // ---- W1 phase: lane owns cols c0..c0+7 (512 = 64 lanes x 8) ----
        const int c0 = lane * 8;
        float4 a0 = {0.f, 0.f, 0.f, 0.f}, a1 = {0.f, 0.f, 0.f, 0.f};
        for (int k0 = 0; k0 < D_INK; k0 += 64) {
            const float xreg = xr[wid][k0 + lane];
            #pragma unroll
            for (int kk = 0; kk < 64; ++kk) {
                const float* wrow = W1 + (size_t)(k0 + kk) * D_HID + c0;
                const float4 w0 = *(const float4*)(wrow);
                const float4 w1 = *(const float4*)(wrow + 4);
                const float xb = rdlane(xreg, kk);
                a0.x = fmaf(xb, w0.x, a0.x); a0.y = fmaf(xb, w0.y, a0.y);
                a0.z = fmaf(xb, w0.z, a0.z); a0.w = fmaf(xb, w0.w, a0.w);
                a1.x = fmaf(xb, w1.x, a1.x); a1.y = fmaf(xb, w1.y, a1.y);
                a1.z = fmaf(xb, w1.z, a1.z); a1.w = fmaf(xb, w1.w, a1.w);
            }
        }
        {
            const float4 bb0 = *(const float4*)(b1 + c0);
            const float4 bb1 = *(const float4*)(b1 + c0 + 4);
            float4 h0, h1;
            h0.x = fmaxf(a0.x + bb0.x, 0.f); h0.y = fmaxf(a0.y + bb0.y, 0.f);
            h0.z = fmaxf(a0.z + bb0.z, 0.f); h0.w = fmaxf(a0.w + bb0.w, 0.f);
            h1.x = fmaxf(a1.x + bb1.x, 0.f); h1.y = fmaxf(a1.y + bb1.y, 0.f);
            h1.z = fmaxf(a1.z + bb1.z, 0.f); h1.w = fmaxf(a1.w + bb1.w, 0.f);
            *(float4*)&hr[wid][c0]     = h0;
            *(float4*)&hr[wid][c0 + 4] = h1;
        }

        // ---- W2 phase: lane owns cols d0..d0+3 (256 = 64 x 4) ----
        const int d0 = lane * 4;
        float4 e4 = {0.f, 0.f, 0.f, 0.f};
        for (int k0 = 0; k0 < D_HID; k0 += 64) {
            const float hreg = hr[wid][k0 + lane];
            #pragma unroll
            for (int kk = 0; kk < 64; ++kk) {
                const float4 wv = *(const float4*)(W2 + (size_t)(k0 + kk) * D_CODE_ + d0);
                const float hb = rdlane(hreg, kk);
                e4.x = fmaf(hb, wv.x, e4.x); e4.y = fmaf(hb, wv.y, e4.y);
                e4.z = fmaf(hb, wv.z, e4.z); e4.w = fmaf(hb, wv.w, e4.w);
            }
        }
        {
            const float4 bb = *(const float4*)(b2 + d0);
            float4 ev;
            ev.x = e4.x + bb.x; ev.y = e4.y + bb.y;
            ev.z = e4.z + bb.z; ev.w = e4.w + bb.w;
            *(float4*)&er[wid][d0] = ev;
        }

        // ---- distance phase: lane owns codes j0, j0+1 (128 = 64 x 2) ----
        const int j0 = lane * 2;
        float e2 = 0.f, dt0 = 0.f, dt1 = 0.f;
        for (int k0 = 0; k0 < D_CODE_; k0 += 64) {
            const float ereg = er[wid][k0 + lane];
            #pragma unroll
            for (int kk = 0; kk < 64; ++kk) {
                const float2 cv = *(const float2*)(cbT + (size_t)(k0 + kk) * N_CODES_ + j0);
                const float ev = rdlane(ereg, kk);
                e2  = fmaf(ev, ev, e2);
                dt0 = fmaf(ev, cv.x, dt0);
                dt1 = fmaf(ev, cv.y, dt1);
            }
        }
        const float dva = (e2 - 2.0f * dt0) + cbnorm[j0];
        const float dvb = (e2 - 2.0f * dt1) + cbnorm[j0 + 1];
        float bv; int bi;
        if (dvb < dva) { bv = dvb; bi = j0 + 1; } else { bv = dva; bi = j0; }

        // wave-wide argmin (first-occurrence tie-break)
        #pragma unroll
        for (int mk = 1; mk <= 32; mk <<= 1) {
            const float ov = __shfl_xor(bv, mk);
            const int   oi = __shfl_xor(bi, mk);
            if (ov < bv || (ov == bv && oi < bi)) { bv = ov; bi = oi; }
        }
        if (lane == 0) outIdx[row] = (float)bi;
    }
}

// ---------------------------------------------------------------------------
__global__ void finalize_kernel(const float* __restrict__ accum, float* __restrict__ out)
{
    const float inv = 1.0f / (32768.0f * 256.0f);
    const float loss = (accum[0] + accum[1]) * inv;   // commitment == codebook
    out[32768] = loss;
    out[32769] = loss;
    out[32770] = 1.25f * loss;
}

// ---------------------------------------------------------------------------
extern "C" void kernel_launch(void* const* d_in, const int* in_sizes, int n_in,
                              void* d_out, int out_size, void* d_ws, size_t ws_size,
                              hipStream_t stream)
{
    (void)in_sizes; (void)n_in; (void)out_size; (void)ws_size;

    const float* x  = (const float*)d_in[0];  // [32768,1024]
    const float* W1 = (const float*)d_in[1];  // [1024,512]
    const float* b1 = (const float*)d_in[2];  // [512]
    const float* W2 = (const float*)d_in[3];  // [512,256]
    const float* b2 = (const float*)d_in[4];  // [256]
    const float* cb = (const float*)d_in[5];  // [128,256]
    float* out = (float*)d_out;

    // workspace layout (bytes); encP overlaps xP (xP dead after gemm1)
    char* ws = (char*)d_ws;
    _Float16* W1P  = (_Float16*)(ws + 0);                 // 1 MB   (4 nt x 32 ks)
    _Float16* W2P  = (_Float16*)(ws + 1048576);           // 256 KB (2 nt x 16 ks)
    _Float16* cbP  = (_Float16*)(ws + 1310720);           // 64 KB  (1 nt x 8 ks)
    float*    cbn  = (float*   )(ws + 1376256);           // 512 B
    float*    accum= (float*   )(ws + 1376768);           // 64 B
    int*      cnt  = (int*     )(ws + 1376832);           // 64 B
    int*      list = (int*     )(ws + 1376896);           // 128 KB
    float*    cbT  = (float*   )(ws + 1507968);           // 128 KB fp32 [256][128]
    _Float16* xP   = (_Float16*)(ws + (size_t)(2u<<20));              // 64 MB
    _Float16* encP = (_Float16*)(ws + (size_t)(2u<<20));              // 16 MB (reuse)
    _Float16* hP   = (_Float16*)(ws + (size_t)(2u<<20) + 67108864);   // 32 MB

    prep_cb_kernel<<<N_CODES_, 256, 0, stream>>>(cb, cbP, cbT, cbn, accum, cnt);
    pack_w_kernel<<<dim3(D_INK / 32, D_HID / 128), 256, 0, stream>>>(W1, W1P, D_INK, D_HID);
    pack_w_kernel<<<dim3(D_HID / 32, D_CODE_ / 128), 256, 0, stream>>>(W2, W2P, D_HID, D_CODE_);
    pack_x_kernel<<<dim3(M_ROWS / 128, D_INK / 128), 256, 0, stream>>>(x, xP);

    gemm1_kernel<<<(M_ROWS / 128) * (D_HID / 128), 256, 0, stream>>>(xP, W1P, b1, hP);
    gemm2_kernel<<<(M_ROWS / 128) * (D_CODE_ / 128), 256, 0, stream>>>(hP, W2P, b2, encP, accum);
    dist_kernel<<<M_ROWS / 128, 256, 0, stream>>>(encP, cbP, cbn, out, accum, cnt, list);
    fixup_kernel<<<512, 512, 0, stream>>>(x, W1, b1, W2, b2, cbT, cbn, cnt, list, out);
    finalize_kernel<<<1, 1, 0, stream>>>(accum, out);
}

// Round 14
// 246.455 us; speedup vs baseline: 2.0084x; 2.0084x over previous
//
#include <hip/hip_runtime.h>
#include <cstddef>
#include <cstdint>

// Problem constants
static constexpr int M_ROWS  = 32768;   // B*T
static constexpr int D_INK   = 1024;
static constexpr int D_HID   = 512;
static constexpr int D_CODE_ = 256;
static constexpr int N_CODES_= 128;

// fp16 single-product pairwise-d2 gap jitter sigma ~= 0.023 -> TAU = 6.5 sigma
static constexpr float TAU_GAP = 0.15f;

using f16x8 = __attribute__((ext_vector_type(8))) _Float16;
using f32x4 = __attribute__((ext_vector_type(4))) float;
using f32x2 = __attribute__((ext_vector_type(2))) float;

__device__ __forceinline__ float rdlane(float v, int kk) {
    return __uint_as_float(__builtin_amdgcn_readlane(__float_as_uint(v), kk));
}

// ---------------------------------------------------------------------------
// Packed panel format: one panel = one (128-row tile) x (32-k step):
//   panel[(kq*128 + rc)*8 + j] = src[tile*128 + rc][ks*32 + kq*8 + j]
// 4096 x fp16 = 8 KB contiguous; frag-linear == the LDS layout the MFMA
// fragment reads want, so global->LDS DMA is fully coalesced AND linear.
// ---------------------------------------------------------------------------

__device__ __forceinline__ void dma16(const void* g, void* l) {
    __builtin_amdgcn_global_load_lds(
        (const __attribute__((address_space(1))) void*)g,
        (__attribute__((address_space(3))) void*)l, 16, 0, 0);
}

// stage one 8 KB panel into LDS: 8 dma16 instrs, 2 per wave, lane-contiguous
__device__ __forceinline__ void stage_panel(const _Float16* __restrict__ p,
                                            _Float16* dst, int w, int lane)
{
    #pragma unroll
    for (int ii = 0; ii < 2; ++ii) {
        const int I = 2 * w + ii;           // 0..7 (wave-uniform)
        dma16(p + (size_t)I * 512 + lane * 8, dst + (size_t)I * 512);
    }
}

// one BK=32 compute step: 4x4 fragment tile per wave, single fp16 product
__device__ __forceinline__ void mfma_tile(const _Float16* sA, const _Float16* sB,
                                          int wm, int wn, int kq, int lm,
                                          f32x4 (&acc)[4][4])
{
    f16x8 a[4];
    #pragma unroll
    for (int fm = 0; fm < 4; ++fm)
        a[fm] = *(const f16x8*)(sA + (kq * 128 + wm * 64 + fm * 16 + lm) * 8);
    #pragma unroll
    for (int fn = 0; fn < 4; ++fn) {
        const f16x8 b = *(const f16x8*)(sB + (kq * 128 + wn * 64 + fn * 16 + lm) * 8);
        #pragma unroll
        for (int fm = 0; fm < 4; ++fm)
            acc[fm][fn] = __builtin_amdgcn_mfma_f32_16x16x32_f16(a[fm], b, acc[fm][fn], 0, 0, 0);
    }
}

// bijective XCD swizzle (nwg % 8 == 0): consecutive logical ids -> same XCD L2
__device__ __forceinline__ int xcd_swz(int bid, int nwg) {
    const int q = nwg >> 3;
    return (bid & 7) * q + (bid >> 3);
}

// ---------------------------------------------------------------------------
// prep: codebook -> packed fp16 panels (B-side) + fp32 transposed copy
// (for coalesced fixup distance reads), exact per-code norms, zero accums.
// ---------------------------------------------------------------------------
__global__ __launch_bounds__(256)
void prep_cb_kernel(const float* __restrict__ cb, _Float16* __restrict__ cbP,
                    float* __restrict__ cbT,
                    float* __restrict__ cbnorm, float* __restrict__ accum,
                    int* __restrict__ cnt)
{
    const int j = blockIdx.x;      // code 0..127
    const int t = threadIdx.x;     // dim 0..255
    const float v = cb[j * D_CODE_ + t];
    const int ks = t >> 5, kq = (t >> 3) & 3, jj = t & 7;
    cbP[((size_t)ks * 512 + kq * 128 + j) * 8 + jj] = (_Float16)v;
    cbT[(size_t)t * N_CODES_ + j] = v;

    __shared__ float sr[256];
    sr[t] = v * v;
    __syncthreads();
    for (int s = 128; s >= 1; s >>= 1) {
        if (t < s) sr[t] += sr[t + s];
        __syncthreads();
    }
    if (t == 0) cbnorm[j] = sr[0];
    if (j == 0 && t < 2) accum[t] = 0.0f;
    if (j == 0 && t == 2) *cnt = 0;
}

// ---------------------------------------------------------------------------
// pack_w: W [K][N] fp32 -> B-side panels (n-tiles of 128, k-steps of 32).
// ---------------------------------------------------------------------------
__global__ __launch_bounds__(256)
void pack_w_kernel(const float* __restrict__ W, _Float16* __restrict__ WP,
                   int Kd, int Nd)
{
    const int ks = blockIdx.x, nt = blockIdx.y;
    const int t = threadIdx.x;
    _Float16* dst = WP + ((size_t)nt * (Kd >> 5) + ks) * 4096;
    #pragma unroll
    for (int half = 0; half < 2; ++half) {
        const int f = half * 256 + t;
        const int nc = f & 127, kq = f >> 7;
        f16x8 v;
        #pragma unroll
        for (int j = 0; j < 8; ++j)
            v[j] = (_Float16)W[(size_t)(ks * 32 + kq * 8 + j) * Nd + nt * 128 + nc];
        *(f16x8*)(dst + (size_t)f * 8) = v;
    }
}

// ---------------------------------------------------------------------------
// pack_x: x fp32 [M][1024] -> A-side fp16 panels.  Coalesced reads,
// LDS-tiled, contiguous panel writes.  grid = (M/128, 8).
// ---------------------------------------------------------------------------
__global__ __launch_bounds__(256)
void pack_x_kernel(const float* __restrict__ X, _Float16* __restrict__ XP)
{
    __shared__ _Float16 sh[128][136];   // 272 B rows: 16B-aligned frag reads
    const int t  = threadIdx.x;
    const int mt = blockIdx.x;          // m-tile
    const int kc = blockIdx.y;          // 128-wide k chunk (4 k-steps)

    const float* src = X + (size_t)mt * 128 * D_INK + kc * 128;
    #pragma unroll
    for (int i = 0; i < 16; ++i) {
        const int idx = i * 256 + t;           // 0..4095
        const int row = idx >> 5, c4 = idx & 31;
        const float4 v = *(const float4*)(src + (size_t)row * D_INK + c4 * 4);
        _Float16* d = &sh[row][c4 * 4];
        d[0] = (_Float16)v.x; d[1] = (_Float16)v.y;
        d[2] = (_Float16)v.z; d[3] = (_Float16)v.w;
    }
    __syncthreads();

    _Float16* dst = XP + ((size_t)mt * 32 + kc * 4) * 4096;
    #pragma unroll
    for (int s = 0; s < 4; ++s) {
        #pragma unroll
        for (int half = 0; half < 2; ++half) {
            const int f = half * 256 + t;
            const int rc = f & 127, kq = f >> 7;
            const f16x8 v = *(const f16x8*)(&sh[rc][s * 32 + kq * 8]);
            *(f16x8*)(dst + (size_t)s * 4096 + (size_t)f * 8) = v;
        }
    }
}

// ---------------------------------------------------------------------------
// GEMM1: h = relu(x @ W1 + b1).  All-packed-DMA staging, dbuf LDS (32 KB),
// one __syncthreads per K-step, 4 blocks/CU, XCD-swizzled n-fast grid.
// Output written directly in gemm2's packed-A layout.
// ---------------------------------------------------------------------------
__global__ __launch_bounds__(256, 4)
void gemm1_kernel(const _Float16* __restrict__ AP, const _Float16* __restrict__ BP,
                  const float* __restrict__ bias, _Float16* __restrict__ CP)
{
    __shared__ _Float16 lds[2][2][4096];   // [buf][A,B]  32 KB

    const int tid  = threadIdx.x;
    const int lane = tid & 63;
    const int w    = tid >> 6;
    const int wm = w >> 1, wn = w & 1;
    const int kq = lane >> 4, lm = lane & 15;

    const int swz = xcd_swz(blockIdx.x, (M_ROWS / 128) * (D_HID / 128));
    const int n0 = (swz & 3) * 128;
    const int m0 = (swz >> 2) * 128;

    const _Float16* Apan = AP + ((size_t)(m0 >> 7) * 32) * 4096;
    const _Float16* Bpan = BP + ((size_t)(n0 >> 7) * 32) * 4096;

    f32x4 acc[4][4] = {};

    stage_panel(Apan, &lds[0][0][0], w, lane);
    stage_panel(Bpan, &lds[0][1][0], w, lane);

    constexpr int NSTEP = D_INK / 32;
    for (int t = 0; t < NSTEP; ++t) {
        const int cur = t & 1, nxt = cur ^ 1;
        __syncthreads();               // buf[cur] staged & visible, buf[nxt] free
        if (t + 1 < NSTEP) {
            stage_panel(Apan + (size_t)(t + 1) * 4096, &lds[nxt][0][0], w, lane);
            stage_panel(Bpan + (size_t)(t + 1) * 4096, &lds[nxt][1][0], w, lane);
        }
        mfma_tile(&lds[cur][0][0], &lds[cur][1][0], wm, wn, kq, lm, acc);
    }

    // epilogue: relu; write in gemm2-packed-A layout (NT=16 over D_HID)
    #pragma unroll
    for (int fn = 0; fn < 4; ++fn) {
        const int col = n0 + wn * 64 + fn * 16 + lm;
        const float bv = bias[col];
        #pragma unroll
        for (int fm = 0; fm < 4; ++fm) {
            #pragma unroll
            for (int r = 0; r < 4; ++r) {
                const int row = m0 + wm * 64 + fm * 16 + kq * 4 + r;
                const float v = fmaxf(acc[fm][fn][r] + bv, 0.0f);
                CP[(((size_t)(row >> 7) * 16 + (col >> 5)) * 512
                    + (size_t)((col >> 3) & 3) * 128 + (row & 127)) * 8 + (col & 7)]
                    = (_Float16)v;
            }
        }
    }
}

// ---------------------------------------------------------------------------
// GEMM2: enc = h @ W2 + b2 (+ sum(enc^2) atomic).  Packed in, packed out.
// ---------------------------------------------------------------------------
__global__ __launch_bounds__(256, 4)
void gemm2_kernel(const _Float16* __restrict__ AP, const _Float16* __restrict__ BP,
                  const float* __restrict__ bias, _Float16* __restrict__ CP,
                  float* __restrict__ accum)
{
    __shared__ _Float16 lds[2][2][4096];

    const int tid  = threadIdx.x;
    const int lane = tid & 63;
    const int w    = tid >> 6;
    const int wm = w >> 1, wn = w & 1;
    const int kq = lane >> 4, lm = lane & 15;

    const int swz = xcd_swz(blockIdx.x, (M_ROWS / 128) * (D_CODE_ / 128));
    const int n0 = (swz & 1) * 128;
    const int m0 = (swz >> 1) * 128;

    const _Float16* Apan = AP + ((size_t)(m0 >> 7) * 16) * 4096;
    const _Float16* Bpan = BP + ((size_t)(n0 >> 7) * 16) * 4096;

    f32x4 acc[4][4] = {};

    stage_panel(Apan, &lds[0][0][0], w, lane);
    stage_panel(Bpan, &lds[0][1][0], w, lane);

    constexpr int NSTEP = D_HID / 32;
    for (int t = 0; t < NSTEP; ++t) {
        const int cur = t & 1, nxt = cur ^ 1;
        __syncthreads();
        if (t + 1 < NSTEP) {
            stage_panel(Apan + (size_t)(t + 1) * 4096, &lds[nxt][0][0], w, lane);
            stage_panel(Bpan + (size_t)(t + 1) * 4096, &lds[nxt][1][0], w, lane);
        }
        mfma_tile(&lds[cur][0][0], &lds[cur][1][0], wm, wn, kq, lm, acc);
    }

    float sumsq = 0.0f;
    #pragma unroll
    for (int fn = 0; fn < 4; ++fn) {
        const int col = n0 + wn * 64 + fn * 16 + lm;
        const float bv = bias[col];
        #pragma unroll
        for (int fm = 0; fm < 4; ++fm) {
            #pragma unroll
            for (int r = 0; r < 4; ++r) {
                const int row = m0 + wm * 64 + fm * 16 + kq * 4 + r;
                const float v = acc[fm][fn][r] + bv;
                sumsq = fmaf(v, v, sumsq);
                CP[(((size_t)(row >> 7) * 8 + (col >> 5)) * 512
                    + (size_t)((col >> 3) & 3) * 128 + (row & 127)) * 8 + (col & 7)]
                    = (_Float16)v;
            }
        }
    }
    #pragma unroll
    for (int mk = 1; mk <= 32; mk <<= 1) sumsq += __shfl_xor(sumsq, mk);
    if (lane == 0) atomicAdd(&accum[1], sumsq);
}

// ---------------------------------------------------------------------------
// dist: dots = enc @ cb^T (one n-block = all 128 codes); argmin epilogue
// with second-best gap flagging + min-term loss sum.
// ---------------------------------------------------------------------------
__global__ __launch_bounds__(256, 4)
void dist_kernel(const _Float16* __restrict__ AP, const _Float16* __restrict__ BP,
                 const float* __restrict__ cbn,
                 float* __restrict__ outIdx, float* __restrict__ accum,
                 int* __restrict__ cnt, int* __restrict__ list)
{
    __shared__ _Float16 lds[2][2][4096];

    const int tid  = threadIdx.x;
    const int lane = tid & 63;
    const int w    = tid >> 6;
    const int wm = w >> 1, wn = w & 1;
    const int kq = lane >> 4, lm = lane & 15;
    const int m0 = blockIdx.x * 128;

    float cbn_l[4];
    #pragma unroll
    for (int fn = 0; fn < 4; ++fn) cbn_l[fn] = cbn[wn * 64 + fn * 16 + lm];

    const _Float16* Apan = AP + ((size_t)(m0 >> 7) * 8) * 4096;

    f32x4 acc[4][4] = {};

    stage_panel(Apan, &lds[0][0][0], w, lane);
    stage_panel(BP,   &lds[0][1][0], w, lane);

    constexpr int NSTEP = D_CODE_ / 32;
    for (int t = 0; t < NSTEP; ++t) {
        const int cur = t & 1, nxt = cur ^ 1;
        __syncthreads();
        if (t + 1 < NSTEP) {
            stage_panel(Apan + (size_t)(t + 1) * 4096, &lds[nxt][0][0], w, lane);
            stage_panel(BP   + (size_t)(t + 1) * 4096, &lds[nxt][1][0], w, lane);
        }
        mfma_tile(&lds[cur][0][0], &lds[cur][1][0], wm, wn, kq, lm, acc);
    }

    __syncthreads();   // all LDS reads done before reuse as epilogue scratch
    float* eb1 = (float*)&lds[0][0][0];        // [2][128]
    float* eb2 = eb1 + 256;
    int*   eix = (int*)(eb2 + 256);

    #pragma unroll
    for (int fm = 0; fm < 4; ++fm) {
        #pragma unroll
        for (int r = 0; r < 4; ++r) {
            float b1v = 3.4e38f, b2v = 3.4e38f; int bi = 0;
            #pragma unroll
            for (int fn = 0; fn < 4; ++fn) {
                const float v = fmaf(-2.0f, acc[fm][fn][r], cbn_l[fn]);
                if (v < b1v) { b2v = b1v; b1v = v; bi = wn * 64 + fn * 16 + lm; }
                else if (v < b2v) b2v = v;
            }
            #pragma unroll
            for (int mk = 1; mk <= 8; mk <<= 1) {
                const float o1 = __shfl_xor(b1v, mk);
                const float o2 = __shfl_xor(b2v, mk);
                const int   oi = __shfl_xor(bi,  mk);
                if (o1 < b1v || (o1 == b1v && oi < bi)) { b2v = fminf(b1v, o2); b1v = o1; bi = oi; }
                else b2v = fminf(b2v, o1);
            }
            const int rl = wm * 64 + fm * 16 + kq * 4 + r;
            if (lm == 0) { eb1[wn * 128 + rl] = b1v; eb2[wn * 128 + rl] = b2v; eix[wn * 128 + rl] = bi; }
        }
    }
    __syncthreads();

    if (tid < 128) {
        const int rl = tid;
        const float a1 = eb1[rl], a2 = eb2[rl]; const int ai = eix[rl];
        const float o1 = eb1[128 + rl], o2 = eb2[128 + rl]; const int oi = eix[128 + rl];
        float B1, B2; int BI;
        if (o1 < a1 || (o1 == a1 && oi < ai)) { B1 = o1; BI = oi; B2 = fminf(a1, o2); }
        else                                  { B1 = a1; BI = ai; B2 = fminf(a2, o1); }
        outIdx[m0 + rl] = (float)BI;
        if (B2 - B1 < TAU_GAP) { const int p = atomicAdd(cnt, 1); list[p] = m0 + rl; }
        float s = B1;
        #pragma unroll
        for (int mk = 1; mk <= 32; mk <<= 1) s += __shfl_xor(s, mk);
        if (lane == 0) atomicAdd(&accum[0], s);
    }
}

// ---------------------------------------------------------------------------
// fixup v6: round-10 structure (8 rows/group, 256 threads, register weight
// reuse across rows via rdlane) + pk_fma accumulators + 8-deep explicit
// load-prefetch rings.  No barriers inside the k loops.  Per-output
// accumulation order: single k-ascending chain (identical numerics).
// ---------------------------------------------------------------------------
__global__ __launch_bounds__(256)
void fixup_kernel(const float* __restrict__ x, const float* __restrict__ W1,
                  const float* __restrict__ b1, const float* __restrict__ W2,
                  const float* __restrict__ b2, const float* __restrict__ cbT,
                  const float* __restrict__ cbnorm,
                  const int* __restrict__ cnt, const int* __restrict__ list,
                  float* __restrict__ outIdx)
{
    __shared__ float xr[8][1024];   // 32 KB
    __shared__ float hr[8][512];    // 16 KB
    __shared__ float er[8][256];    //  8 KB
    __shared__ float dv[8][128];    //  4 KB
    __shared__ int   di[8][128];    //  4 KB   -> 64 KB total

    const int tid  = threadIdx.x;
    const int lane = tid & 63;
    const int n = *cnt;
    const int ngroups = (n + 7) >> 3;

    for (int g = blockIdx.x; g < ngroups; g += gridDim.x) {
        const int base = g * 8;
        const int nr = (n - base < 8) ? (n - base) : 8;
        __syncthreads();   // LDS reuse guard across group iterations
        #pragma unroll
        for (int r = 0; r < 8; ++r) {
            if (r < nr) {
                const int row = list[base + r];
                *(float4*)&xr[r][tid * 4] =
                    *(const float4*)(x + (size_t)row * D_INK + tid * 4);
            }
        }
        __syncthreads();

        // ---- W1 phase: thread owns cols (2t, 2t+1), all 8 rows ----
        {
            const int c2 = tid * 2;
            f32x2 a01[8] = {};
            for (int k0 = 0; k0 < D_INK; k0 += 64) {
                float xreg[8];
                #pragma unroll
                for (int r = 0; r < 8; ++r) xreg[r] = xr[r][k0 + lane];
                #pragma unroll
                for (int kb = 0; kb < 64; kb += 8) {
                    f32x2 wv[8];
                    #pragma unroll
                    for (int p = 0; p < 8; ++p)
                        wv[p] = *(const f32x2*)&W1[(size_t)(k0 + kb + p) * D_HID + c2];
                    #pragma unroll
                    for (int p = 0; p < 8; ++p) {
                        const int kk = kb + p;
                        #pragma unroll
                        for (int r = 0; r < 8; ++r) {
                            const float xb = rdlane(xreg[r], kk);
                            a01[r] = __builtin_elementwise_fma((f32x2){xb, xb}, wv[p], a01[r]);
                        }
                    }
                }
            }
            #pragma unroll
            for (int r = 0; r < 8; ++r) {
                hr[r][c2]     = fmaxf(a01[r].x + b1[c2], 0.0f);
                hr[r][c2 + 1] = fmaxf(a01[r].y + b1[c2 + 1], 0.0f);
            }
        }
        __syncthreads();

        // ---- W2 phase: thread owns cols (cc, cc+1), rows half*4..+3 ----
        {
            const int cc = (tid & 127) * 2;
            const int half = tid >> 7;
            f32x2 a2[4] = {};
            for (int k0 = 0; k0 < D_HID; k0 += 64) {
                float hreg[4];
                #pragma unroll
                for (int q = 0; q < 4; ++q) hreg[q] = hr[half * 4 + q][k0 + lane];
                #pragma unroll
                for (int kb = 0; kb < 64; kb += 8) {
                    f32x2 wv[8];
                    #pragma unroll
                    for (int p = 0; p < 8; ++p)
                        wv[p] = *(const f32x2*)&W2[(size_t)(k0 + kb + p) * D_CODE_ + cc];
                    #pragma unroll
                    for (int p = 0; p < 8; ++p) {
                        const int kk = kb + p;
                        #pragma unroll
                        for (int q = 0; q < 4; ++q) {
                            const float hb = rdlane(hreg[q], kk);
                            a2[q] = __builtin_elementwise_fma((f32x2){hb, hb}, wv[p], a2[q]);
                        }
                    }
                }
            }
            #pragma unroll
            for (int q = 0; q < 4; ++q) {
                er[half * 4 + q][cc]     = a2[q].x + b2[cc];
                er[half * 4 + q][cc + 1] = a2[q].y + b2[cc + 1];
            }
        }
        __syncthreads();

        // ---- distance phase: thread owns code j, rows half*4..+3 ----
        {
            const int j = tid & 127;
            const int half = tid >> 7;
            float e2[4], dt[4];
            #pragma unroll
            for (int q = 0; q < 4; ++q) { e2[q] = 0.0f; dt[q] = 0.0f; }
            for (int k0 = 0; k0 < D_CODE_; k0 += 64) {
                float ereg[4];
                #pragma unroll
                for (int q = 0; q < 4; ++q) ereg[q] = er[half * 4 + q][k0 + lane];
                #pragma unroll
                for (int kb = 0; kb < 64; kb += 8) {
                    float cv[8];
                    #pragma unroll
                    for (int p = 0; p < 8; ++p)
                        cv[p] = cbT[(size_t)(k0 + kb + p) * N_CODES_ + j];
                    #pragma unroll
                    for (int p = 0; p < 8; ++p) {
                        const int kk = kb + p;
                        #pragma unroll
                        for (int q = 0; q < 4; ++q) {
                            const float ev = rdlane(ereg[q], kk);
                            e2[q] = fmaf(ev, ev, e2[q]);
                            dt[q] = fmaf(ev, cv[p], dt[q]);
                        }
                    }
                }
            }
            #pragma unroll
            for (int q = 0; q < 4; ++q) {
                dv[half * 4 + q][j] = (e2[q] - 2.0f * dt[q]) + cbnorm[j];
                di[half * 4 + q][j] = j;
            }
        }
        __syncthreads();

        // ---- argmin reduce: 2 rows per pass, 4 passes ----
        #pragma unroll
        for (int pass = 0; pass < 4; ++pass) {
            const int r = pass * 2 + (tid >> 7);
            const int i = tid & 127;
            for (int st = 64; st >= 1; st >>= 1) {
                if (i < st) {
                    const float a = dv[r][i], b = dv[r][i + st];
                    const int  ib = di[r][i + st];
                    if (b < a || (b == a && ib < di[r][i])) { dv[r][i] = b; di[r][i] = ib; }
                }
                __syncthreads();
            }
        }
        if (tid < nr) outIdx[list[base + tid]] = (float)di[tid][0];
    }
}

// ---------------------------------------------------------------------------
__global__ void finalize_kernel(const float* __restrict__ accum, float* __restrict__ out)
{
    const float inv = 1.0f / (32768.0f * 256.0f);
    const float loss = (accum[0] + accum[1]) * inv;   // commitment == codebook
    out[32768] = loss;
    out[32769] = loss;
    out[32770] = 1.25f * loss;
}

// ---------------------------------------------------------------------------
extern "C" void kernel_launch(void* const* d_in, const int* in_sizes, int n_in,
                              void* d_out, int out_size, void* d_ws, size_t ws_size,
                              hipStream_t stream)
{
    (void)in_sizes; (void)n_in; (void)out_size; (void)ws_size;

    const float* x  = (const float*)d_in[0];  // [32768,1024]
    const float* W1 = (const float*)d_in[1];  // [1024,512]
    const float* b1 = (const float*)d_in[2];  // [512]
    const float* W2 = (const float*)d_in[3];  // [512,256]
    const float* b2 = (const float*)d_in[4];  // [256]
    const float* cb = (const float*)d_in[5];  // [128,256]
    float* out = (float*)d_out;

    // workspace layout (bytes); encP overlaps xP (xP dead after gemm1)
    char* ws = (char*)d_ws;
    _Float16* W1P  = (_Float16*)(ws + 0);                 // 1 MB   (4 nt x 32 ks)
    _Float16* W2P  = (_Float16*)(ws + 1048576);           // 256 KB (2 nt x 16 ks)
    _Float16* cbP  = (_Float16*)(ws + 1310720);           // 64 KB  (1 nt x 8 ks)
    float*    cbn  = (float*   )(ws + 1376256);           // 512 B
    float*    accum= (float*   )(ws + 1376768);           // 64 B
    int*      cnt  = (int*     )(ws + 1376832);           // 64 B
    int*      list = (int*     )(ws + 1376896);           // 128 KB
    float*    cbT  = (float*   )(ws + 1507968);           // 128 KB fp32 [256][128]
    _Float16* xP   = (_Float16*)(ws + (size_t)(2u<<20));              // 64 MB
    _Float16* encP = (_Float16*)(ws + (size_t)(2u<<20));              // 16 MB (reuse)
    _Float16* hP   = (_Float16*)(ws + (size_t)(2u<<20) + 67108864);   // 32 MB

    prep_cb_kernel<<<N_CODES_, 256, 0, stream>>>(cb, cbP, cbT, cbn, accum, cnt);
    pack_w_kernel<<<dim3(D_INK / 32, D_HID / 128), 256, 0, stream>>>(W1, W1P, D_INK, D_HID);
    pack_w_kernel<<<dim3(D_HID / 32, D_CODE_ / 128), 256, 0, stream>>>(W2, W2P, D_HID, D_CODE_);
    pack_x_kernel<<<dim3(M_ROWS / 128, D_INK / 128), 256, 0, stream>>>(x, xP);

    gemm1_kernel<<<(M_ROWS / 128) * (D_HID / 128), 256, 0, stream>>>(xP, W1P, b1, hP);
    gemm2_kernel<<<(M_ROWS / 128) * (D_CODE_ / 128), 256, 0, stream>>>(hP, W2P, b2, encP, accum);
    dist_kernel<<<M_ROWS / 128, 256, 0, stream>>>(encP, cbP, cbn, out, accum, cnt, list);
    fixup_kernel<<<512, 256, 0, stream>>>(x, W1, b1, W2, b2, cbT, cbn, cnt, list, out);
    finalize_kernel<<<1, 1, 0, stream>>>(accum, out);
}